// Round 1
// baseline (2078.528 us; speedup 1.0000x reference)
//
#include <hip/hip_runtime.h>
#include <math.h>

#define B 8
#define C 128
#define H 96
#define W 96
#define HW (H*W)         // 9216
#define OFFC 27
#define EPS 1e-5f
#define TPX 32           // pixels per dcn block

// ---------------- weight transpose: w[oc][ic][k] -> wt[(ic*9+k)*C + oc] ----
__global__ void wt_transpose(const float* __restrict__ w, float* __restrict__ wt) {
    int i = blockIdx.x * 256 + threadIdx.x;
    if (i >= C * C * 9) return;
    int k  = i % 9;
    int ic = (i / 9) % C;
    int oc = i / (9 * C);
    wt[(ic * 9 + k) * C + oc] = w[i];
}

// ---------------- offset conv: 3x3, C->27, pad 1 ---------------------------
// thread per (b, group g of 9 oc, pixel p)
__global__ __launch_bounds__(256) void offset_conv(
    const float* __restrict__ x, const float* __restrict__ ow,
    const float* __restrict__ ob, float* __restrict__ om)
{
    int idx = blockIdx.x * 256 + threadIdx.x;
    if (idx >= B * 3 * HW) return;
    int p = idx % HW;
    int g = (idx / HW) % 3;
    int b = idx / (3 * HW);
    int h = p / W, w = p % W;

    float acc[9];
#pragma unroll
    for (int j = 0; j < 9; j++) acc[j] = ob[g * 9 + j];

    const float* xb = x + (size_t)b * C * HW;
    for (int ic = 0; ic < C; ic++) {
        const float* xc = xb + ic * HW;
        const float* wc = ow + (size_t)(g * 9) * C * 9 + ic * 9;
#pragma unroll
        for (int ky = 0; ky < 3; ky++) {
            int y = h + ky - 1;
            if (y < 0 || y >= H) continue;
#pragma unroll
            for (int kx = 0; kx < 3; kx++) {
                int xw = w + kx - 1;
                if (xw < 0 || xw >= W) continue;
                float xv = xc[y * W + xw];
#pragma unroll
                for (int j = 0; j < 9; j++)
                    acc[j] = fmaf(xv, wc[(size_t)j * C * 9 + ky * 3 + kx], acc[j]);
            }
        }
    }
    float* dst = om + (size_t)b * OFFC * HW + p;
#pragma unroll
    for (int j = 0; j < 9; j++) dst[(size_t)(g * 9 + j) * HW] = acc[j];
}

// ---------------- DCNv2 + bias + BN + ReLU ---------------------------------
// block: 256 threads, handles (b, strip of TPX pixels) x all 128 oc
__global__ __launch_bounds__(256) void dcn_kernel(
    const float* __restrict__ x,   // (B,C,H,W)
    const float* __restrict__ om,  // (B,27,H,W)
    const float* __restrict__ wt,  // [(ic*9+k)*C + oc]
    const float* __restrict__ bias,
    const float* __restrict__ bn_g, const float* __restrict__ bn_b,
    const float* __restrict__ bn_m, const float* __restrict__ bn_v,
    float* __restrict__ out)
{
    __shared__ int   s_idx[TPX * 9 * 4];
    __shared__ float s_wgt[TPX * 9 * 4];
    __shared__ float s_patch[16 * 9 * TPX];   // ic-chunk=16

    int blk  = blockIdx.x;
    int tile = blk % (HW / TPX);
    int b    = blk / (HW / TPX);
    int p0   = tile * TPX;
    int t    = threadIdx.x;

    // bilinear params per (k, px)
    for (int e = t; e < TPX * 9; e += 256) {
        int px = e % TPX;
        int k  = e / TPX;
        int p  = p0 + px;
        int h  = p / W, w = p % W;
        const float* omb = om + (size_t)b * OFFC * HW + p;
        float dy = omb[(size_t)(2 * k) * HW];
        float dx = omb[(size_t)(2 * k + 1) * HW];
        float mk = omb[(size_t)(18 + k) * HW];
        float m  = 1.f / (1.f + __expf(-mk));
        float py = (float)h - 1.f + (float)(k / 3) + dy;
        float pxx = (float)w - 1.f + (float)(k % 3) + dx;
        float y0f = floorf(py), x0f = floorf(pxx);
        float wy1 = py - y0f, wx1 = pxx - x0f;
        int y0 = (int)y0f, x0 = (int)x0f;
#pragma unroll
        for (int j = 0; j < 4; j++) {
            int yy = y0 + (j >> 1);
            int xx = x0 + (j & 1);
            float wg = ((j >> 1) ? wy1 : 1.f - wy1) * ((j & 1) ? wx1 : 1.f - wx1) * m;
            bool valid = (yy >= 0) & (yy < H) & (xx >= 0) & (xx < W);
            int yc = min(max(yy, 0), H - 1);
            int xc = min(max(xx, 0), W - 1);
            s_idx[e * 4 + j] = yc * W + xc;
            s_wgt[e * 4 + j] = valid ? wg : 0.f;
        }
    }
    __syncthreads();

    int oc = t & 127;
    int pg = t >> 7;        // pixel-half 0/1
    float acc[16];
#pragma unroll
    for (int j = 0; j < 16; j++) acc[j] = 0.f;

    const float* xb = x + (size_t)b * C * HW;
    for (int c0 = 0; c0 < C; c0 += 16) {
        __syncthreads();
        // stage patches for this ic chunk
        for (int e = t; e < 16 * 9 * TPX; e += 256) {
            int px  = e % TPX;
            int kk  = e / TPX;   // icl*9 + k
            int k   = kk % 9;
            int icl = kk / 9;
            const float* xc = xb + (size_t)(c0 + icl) * HW;
            int be = (k * TPX + px) * 4;
            float v = s_wgt[be + 0] * xc[s_idx[be + 0]]
                    + s_wgt[be + 1] * xc[s_idx[be + 1]]
                    + s_wgt[be + 2] * xc[s_idx[be + 2]]
                    + s_wgt[be + 3] * xc[s_idx[be + 3]];
            s_patch[e] = v;
        }
        __syncthreads();
        // register-blocked GEMM: 144 (ic,k) steps
        for (int s = 0; s < 16 * 9; s++) {
            float wv = wt[(size_t)(c0 * 9 + s) * C + oc];
            const float* pp = &s_patch[s * TPX + pg * 16];
#pragma unroll
            for (int j = 0; j < 16; j++) acc[j] = fmaf(wv, pp[j], acc[j]);
        }
    }

    float scale = bn_g[oc] * rsqrtf(bn_v[oc] + EPS);
    float shift = bn_b[oc] - bn_m[oc] * scale;
    float bi    = bias[oc];
    float* dst  = out + ((size_t)b * C + oc) * HW + p0 + pg * 16;
#pragma unroll
    for (int j = 0; j < 16; j++) {
        float v = (acc[j] + bi) * scale + shift;
        dst[j] = fmaxf(v, 0.f);
    }
}

// ---------------- per-(b,c) max & mean reduce ------------------------------
__global__ __launch_bounds__(256) void reduce_bc(
    const float* __restrict__ o2, float* __restrict__ mx, float* __restrict__ av)
{
    int bc = blockIdx.x;
    const float* p = o2 + (size_t)bc * HW;
    int t = threadIdx.x;
    float m = -INFINITY, s = 0.f;
    for (int i = t; i < HW; i += 256) {
        float v = p[i];
        m = fmaxf(m, v);
        s += v;
    }
    __shared__ float sm[256], ss[256];
    sm[t] = m; ss[t] = s;
    __syncthreads();
    for (int off = 128; off > 0; off >>= 1) {
        if (t < off) {
            sm[t] = fmaxf(sm[t], sm[t + off]);
            ss[t] += ss[t + off];
        }
        __syncthreads();
    }
    if (t == 0) {
        mx[bc] = sm[0];
        av[bc] = ss[0] / (float)HW;
    }
}

// ---------------- channel attention MLP + sigmoid --------------------------
// block per b, 128 threads
__global__ __launch_bounds__(128) void cam_gate(
    const float* __restrict__ mx, const float* __restrict__ av,
    const float* __restrict__ w1, const float* __restrict__ w2,
    float* __restrict__ ch)
{
    int b = blockIdx.x;
    int t = threadIdx.x;
    __shared__ float smx[C], sav[C], h1[32], h2[32];
    smx[t] = mx[b * C + t];
    sav[t] = av[b * C + t];
    __syncthreads();
    if (t < 32) {
        float a = 0.f, c = 0.f;
        for (int i = 0; i < C; i++) {
            float w = w1[t * C + i];
            a = fmaf(smx[i], w, a);
            c = fmaf(sav[i], w, c);
        }
        h1[t] = fmaxf(a, 0.f);
        h2[t] = fmaxf(c, 0.f);
    }
    __syncthreads();
    float a = 0.f;
#pragma unroll
    for (int j = 0; j < 32; j++) a += (h1[j] + h2[j]) * w2[t * 32 + j];
    ch[b * C + t] = 1.f / (1.f + __expf(-a));
}

// ---------------- final gating scale ---------------------------------------
__global__ __launch_bounds__(256) void scale_out(
    const float* __restrict__ o2, const float* __restrict__ ch,
    float* __restrict__ out)
{
    int e = blockIdx.x * 256 + threadIdx.x;   // float4 index
    if (e >= B * C * HW / 4) return;
    int bc = e / (HW / 4);
    float g = ch[bc];
    float4 v = reinterpret_cast<const float4*>(o2)[e];
    v.x *= g; v.y *= g; v.z *= g; v.w *= g;
    reinterpret_cast<float4*>(out)[e] = v;
}

extern "C" void kernel_launch(void* const* d_in, const int* in_sizes, int n_in,
                              void* d_out, int out_size, void* d_ws, size_t ws_size,
                              hipStream_t stream) {
    const float* x      = (const float*)d_in[0];
    const float* off_w1 = (const float*)d_in[1];
    const float* off_b1 = (const float*)d_in[2];
    const float* dcn_w1 = (const float*)d_in[3];
    const float* dcn_b1 = (const float*)d_in[4];
    const float* bn_g1  = (const float*)d_in[5];
    const float* bn_b1  = (const float*)d_in[6];
    const float* bn_m1  = (const float*)d_in[7];
    const float* bn_v1  = (const float*)d_in[8];
    const float* off_w2 = (const float*)d_in[9];
    const float* off_b2 = (const float*)d_in[10];
    const float* dcn_w2 = (const float*)d_in[11];
    const float* dcn_b2 = (const float*)d_in[12];
    const float* bn_g2  = (const float*)d_in[13];
    const float* bn_b2  = (const float*)d_in[14];
    const float* bn_m2  = (const float*)d_in[15];
    const float* bn_v2  = (const float*)d_in[16];
    const float* cam_w1 = (const float*)d_in[17];
    const float* cam_w2 = (const float*)d_in[18];
    float* out = (float*)d_out;

    float* ws  = (float*)d_ws;
    float* om  = ws;                    // 8*27*9216 = 1,990,656
    float* o1  = om  + 1990656;         // 9,437,184
    float* o2  = o1  + 9437184;         // 9,437,184
    float* wt1 = o2  + 9437184;         // 147,456
    float* wt2 = wt1 + 147456;          // 147,456
    float* mxv = wt2 + 147456;          // 1024
    float* avv = mxv + 1024;            // 1024
    float* chv = avv + 1024;            // 1024

    // weight transposes
    wt_transpose<<<576, 256, 0, stream>>>(dcn_w1, wt1);
    wt_transpose<<<576, 256, 0, stream>>>(dcn_w2, wt2);

    // stage 1
    offset_conv<<<(B * 3 * HW + 255) / 256, 256, 0, stream>>>(x, off_w1, off_b1, om);
    dcn_kernel<<<B * (HW / TPX), 256, 0, stream>>>(x, om, wt1, dcn_b1,
                                                   bn_g1, bn_b1, bn_m1, bn_v1, o1);
    // stage 2
    offset_conv<<<(B * 3 * HW + 255) / 256, 256, 0, stream>>>(o1, off_w2, off_b2, om);
    dcn_kernel<<<B * (HW / TPX), 256, 0, stream>>>(o1, om, wt2, dcn_b2,
                                                   bn_g2, bn_b2, bn_m2, bn_v2, o2);
    // channel attention
    reduce_bc<<<B * C, 256, 0, stream>>>(o2, mxv, avv);
    cam_gate<<<B, 128, 0, stream>>>(mxv, avv, cam_w1, cam_w2, chv);
    scale_out<<<(B * C * HW / 4 + 255) / 256, 256, 0, stream>>>(o2, chv, out);
}

// Round 3
// 1444.761 us; speedup vs baseline: 1.4387x; 1.4387x over previous
//
#include <hip/hip_runtime.h>
#include <math.h>

#define B 8
#define C 128
#define H 96
#define W 96
#define HW (H*W)         // 9216
#define EPS 1e-5f
#define LOSC 2048.f
#define ILOSC (1.f/2048.f)

typedef _Float16 half8 __attribute__((ext_vector_type(8)));
typedef float floatx4 __attribute__((ext_vector_type(4)));

// ---- dcn weight -> split f16 (hi, lo*2048), layout wt[oc][kk*128+ic] -------
__global__ void wt_split(const float* __restrict__ w,
                         _Float16* __restrict__ hi, _Float16* __restrict__ lo) {
    int i = blockIdx.x * 256 + threadIdx.x;
    if (i >= C * C * 9) return;
    int oc = i / 1152, r = i % 1152, kk = r >> 7, ic = r & 127;
    float v = w[oc * 1152 + ic * 9 + kk];
    _Float16 h = (_Float16)v;
    hi[i] = h;
    lo[i] = (_Float16)((v - (float)h) * LOSC);
}

// ---- offset weight -> split f16, layout [32 (27+pad)][kk*128+ic] -----------
__global__ void offw_split(const float* __restrict__ w,
                           _Float16* __restrict__ hi, _Float16* __restrict__ lo) {
    int i = blockIdx.x * 256 + threadIdx.x;
    if (i >= 32 * 1152) return;
    int oc = i / 1152, r = i % 1152, kk = r >> 7, ic = r & 127;
    float v = (oc < 27) ? w[oc * 1152 + ic * 9 + kk] : 0.f;
    _Float16 h = (_Float16)v;
    hi[i] = h;
    lo[i] = (_Float16)((v - (float)h) * LOSC);
}

// ---- offset conv via split-f16 MFMA: 3x3 pad-1 conv, C -> 27(pad 32) -------
// block = 256 thr = 4 waves, 64 px; wave = 16 px x 32 oc (2 N-frags)
__global__ __launch_bounds__(256) void off_mfma(
    const float* __restrict__ x,
    const _Float16* __restrict__ wh, const _Float16* __restrict__ wl,
    const float* __restrict__ ob, float* __restrict__ om)
{
    __shared__ int   s_oi[576];
    __shared__ float s_ow[576];

    int blk = blockIdx.x;
    int b = blk / 144;
    int p0 = (blk % 144) * 64;
    int t = threadIdx.x;

    for (int e = t; e < 576; e += 256) {
        int px = e & 63, kk = e >> 6;
        int p = p0 + px, h = p / W, w = p % W;
        int yy = h + kk / 3 - 1, xx = w + kk % 3 - 1;
        bool v = (yy >= 0) & (yy < H) & (xx >= 0) & (xx < W);
        int yc = min(max(yy, 0), H - 1), xc = min(max(xx, 0), W - 1);
        s_oi[px * 9 + kk] = yc * W + xc;
        s_ow[px * 9 + kk] = v ? 1.f : 0.f;
    }
    __syncthreads();

    int wave = t >> 6, lane = t & 63;
    int row = lane & 15, g = lane >> 4;
    int pxl = wave * 16 + row;
    const float* xb = x + (size_t)b * C * HW;

    floatx4 acch[2], accl[2];
#pragma unroll
    for (int nf = 0; nf < 2; nf++) {
        acch[nf] = (floatx4){0.f, 0.f, 0.f, 0.f};
        accl[nf] = (floatx4){0.f, 0.f, 0.f, 0.f};
    }

    for (int kk = 0; kk < 9; kk++) {
        int   iv = s_oi[pxl * 9 + kk];
        float wv = s_ow[pxl * 9 + kk];
#pragma unroll
        for (int icq = 0; icq < 4; icq++) {
            int icb = icq * 32 + g * 8;
            const float* xq = xb + (size_t)icb * HW + iv;
            half8 ah, al;
#pragma unroll
            for (int j = 0; j < 8; j++) {
                float v = wv * xq[j * HW];
                _Float16 h = (_Float16)v;
                ah[j] = h;
                al[j] = (_Float16)((v - (float)h) * LOSC);
            }
            int kb = kk * 128 + icq * 32 + g * 8;
#pragma unroll
            for (int nf = 0; nf < 2; nf++) {
                size_t wo = (size_t)(nf * 16 + row) * 1152 + kb;
                half8 bh = *(const half8*)(wh + wo);
                half8 bl = *(const half8*)(wl + wo);
                acch[nf] = __builtin_amdgcn_mfma_f32_16x16x32_f16(ah, bh, acch[nf], 0, 0, 0);
                accl[nf] = __builtin_amdgcn_mfma_f32_16x16x32_f16(al, bh, accl[nf], 0, 0, 0);
                accl[nf] = __builtin_amdgcn_mfma_f32_16x16x32_f16(ah, bl, accl[nf], 0, 0, 0);
            }
        }
    }

    int pxo = p0 + wave * 16 + g * 4;
#pragma unroll
    for (int nf = 0; nf < 2; nf++) {
        int oc = nf * 16 + row;
        if (oc < 27) {
            float bi = ob[oc];
            float* dst = om + ((size_t)b * 27 + oc) * HW + pxo;
#pragma unroll
            for (int r = 0; r < 4; r++)
                dst[r] = acch[nf][r] + accl[nf][r] * ILOSC + bi;
        }
    }
}

// ---- DCNv2 + bias + BN + ReLU via split-f16 MFMA ---------------------------
// block = 256 thr = 4 waves, 64 px; wave = 16 px x 128 oc (8 N-frags)
__global__ __launch_bounds__(256) void dcn_mfma(
    const float* __restrict__ x, const float* __restrict__ om,
    const _Float16* __restrict__ wh, const _Float16* __restrict__ wl,
    const float* __restrict__ bias,
    const float* __restrict__ bn_g, const float* __restrict__ bn_b,
    const float* __restrict__ bn_m, const float* __restrict__ bn_v,
    float* __restrict__ out)
{
    __shared__ int4   s_idx[576];   // [px*9+kk] 4 corners
    __shared__ float4 s_wgt[576];

    int blk = blockIdx.x;
    int b = blk / 144;
    int p0 = (blk % 144) * 64;
    int t = threadIdx.x;

    int*   si = (int*)s_idx;
    float* sw = (float*)s_wgt;
    for (int e = t; e < 576; e += 256) {
        int px = e & 63, kk = e >> 6;
        int p = p0 + px, h = p / W, w = p % W;
        const float* obp = om + (size_t)b * 27 * HW + p;
        float dy = obp[(size_t)(2 * kk) * HW];
        float dx = obp[(size_t)(2 * kk + 1) * HW];
        float mk = obp[(size_t)(18 + kk) * HW];
        float m  = 1.f / (1.f + __expf(-mk));
        float py  = (float)h - 1.f + (float)(kk / 3) + dy;
        float pxx = (float)w - 1.f + (float)(kk % 3) + dx;
        float y0f = floorf(py), x0f = floorf(pxx);
        float wy1 = py - y0f, wx1 = pxx - x0f;
        int y0 = (int)y0f, x0 = (int)x0f;
#pragma unroll
        for (int j = 0; j < 4; j++) {
            int yy = y0 + (j >> 1), xx = x0 + (j & 1);
            bool v = (yy >= 0) & (yy < H) & (xx >= 0) & (xx < W);
            float wg = ((j >> 1) ? wy1 : 1.f - wy1) * ((j & 1) ? wx1 : 1.f - wx1) * m;
            int yc = min(max(yy, 0), H - 1), xc = min(max(xx, 0), W - 1);
            si[(px * 9 + kk) * 4 + j] = yc * W + xc;
            sw[(px * 9 + kk) * 4 + j] = v ? wg : 0.f;
        }
    }
    __syncthreads();

    int wave = t >> 6, lane = t & 63;
    int row = lane & 15, g = lane >> 4;
    int pxl = wave * 16 + row;
    const float* xb = x + (size_t)b * C * HW;

    floatx4 acch[8], accl[8];
#pragma unroll
    for (int nf = 0; nf < 8; nf++) {
        acch[nf] = (floatx4){0.f, 0.f, 0.f, 0.f};
        accl[nf] = (floatx4){0.f, 0.f, 0.f, 0.f};
    }

    for (int kk = 0; kk < 9; kk++) {
        int4   iv = s_idx[pxl * 9 + kk];
        float4 wv = s_wgt[pxl * 9 + kk];
#pragma unroll
        for (int icq = 0; icq < 4; icq++) {
            int icb = icq * 32 + g * 8;
            const float* xq = xb + (size_t)icb * HW;
            half8 ah, al;
#pragma unroll
            for (int j = 0; j < 8; j++) {
                const float* xj = xq + j * HW;
                float v = wv.x * xj[iv.x] + wv.y * xj[iv.y]
                        + wv.z * xj[iv.z] + wv.w * xj[iv.w];
                _Float16 h = (_Float16)v;
                ah[j] = h;
                al[j] = (_Float16)((v - (float)h) * LOSC);
            }
            int kb = kk * 128 + icq * 32 + g * 8;
#pragma unroll
            for (int nf = 0; nf < 8; nf++) {
                size_t wo = (size_t)(nf * 16 + row) * 1152 + kb;
                half8 bh = *(const half8*)(wh + wo);
                half8 bl = *(const half8*)(wl + wo);
                acch[nf] = __builtin_amdgcn_mfma_f32_16x16x32_f16(ah, bh, acch[nf], 0, 0, 0);
                accl[nf] = __builtin_amdgcn_mfma_f32_16x16x32_f16(al, bh, accl[nf], 0, 0, 0);
                accl[nf] = __builtin_amdgcn_mfma_f32_16x16x32_f16(ah, bl, accl[nf], 0, 0, 0);
            }
        }
    }

    int pxo = p0 + wave * 16 + g * 4;
#pragma unroll
    for (int nf = 0; nf < 8; nf++) {
        int oc = nf * 16 + row;
        float sc = bn_g[oc] * rsqrtf(bn_v[oc] + EPS);
        float sh = bn_b[oc] - bn_m[oc] * sc;
        float bi = bias[oc];
        float* dst = out + ((size_t)b * C + oc) * HW + pxo;
#pragma unroll
        for (int r = 0; r < 4; r++) {
            float v = acch[nf][r] + accl[nf][r] * ILOSC + bi;
            dst[r] = fmaxf(v * sc + sh, 0.f);
        }
    }
}

// ---------------- per-(b,c) max & mean reduce ------------------------------
__global__ __launch_bounds__(256) void reduce_bc(
    const float* __restrict__ o2, float* __restrict__ mx, float* __restrict__ av)
{
    int bc = blockIdx.x;
    const float* p = o2 + (size_t)bc * HW;
    int t = threadIdx.x;
    float m = -INFINITY, s = 0.f;
    for (int i = t; i < HW; i += 256) {
        float v = p[i];
        m = fmaxf(m, v);
        s += v;
    }
    __shared__ float sm[256], ss[256];
    sm[t] = m; ss[t] = s;
    __syncthreads();
    for (int off = 128; off > 0; off >>= 1) {
        if (t < off) {
            sm[t] = fmaxf(sm[t], sm[t + off]);
            ss[t] += ss[t + off];
        }
        __syncthreads();
    }
    if (t == 0) {
        mx[bc] = sm[0];
        av[bc] = ss[0] / (float)HW;
    }
}

// ---------------- channel attention MLP + sigmoid --------------------------
__global__ __launch_bounds__(128) void cam_gate(
    const float* __restrict__ mx, const float* __restrict__ av,
    const float* __restrict__ w1, const float* __restrict__ w2,
    float* __restrict__ ch)
{
    int b = blockIdx.x;
    int t = threadIdx.x;
    __shared__ float smx[C], sav[C], h1[32], h2[32];
    smx[t] = mx[b * C + t];
    sav[t] = av[b * C + t];
    __syncthreads();
    if (t < 32) {
        float a = 0.f, c = 0.f;
        for (int i = 0; i < C; i++) {
            float w = w1[t * C + i];
            a = fmaf(smx[i], w, a);
            c = fmaf(sav[i], w, c);
        }
        h1[t] = fmaxf(a, 0.f);
        h2[t] = fmaxf(c, 0.f);
    }
    __syncthreads();
    float a = 0.f;
#pragma unroll
    for (int j = 0; j < 32; j++) a += (h1[j] + h2[j]) * w2[t * 32 + j];
    ch[b * C + t] = 1.f / (1.f + __expf(-a));
}

// ---------------- final gating scale ---------------------------------------
__global__ __launch_bounds__(256) void scale_out(
    const float* __restrict__ o2, const float* __restrict__ ch,
    float* __restrict__ out)
{
    int e = blockIdx.x * 256 + threadIdx.x;   // float4 index
    if (e >= B * C * HW / 4) return;
    int bc = e / (HW / 4);
    float g = ch[bc];
    float4 v = reinterpret_cast<const float4*>(o2)[e];
    v.x *= g; v.y *= g; v.z *= g; v.w *= g;
    reinterpret_cast<float4*>(out)[e] = v;
}

extern "C" void kernel_launch(void* const* d_in, const int* in_sizes, int n_in,
                              void* d_out, int out_size, void* d_ws, size_t ws_size,
                              hipStream_t stream) {
    const float* x      = (const float*)d_in[0];
    const float* off_w1 = (const float*)d_in[1];
    const float* off_b1 = (const float*)d_in[2];
    const float* dcn_w1 = (const float*)d_in[3];
    const float* dcn_b1 = (const float*)d_in[4];
    const float* bn_g1  = (const float*)d_in[5];
    const float* bn_b1  = (const float*)d_in[6];
    const float* bn_m1  = (const float*)d_in[7];
    const float* bn_v1  = (const float*)d_in[8];
    const float* off_w2 = (const float*)d_in[9];
    const float* off_b2 = (const float*)d_in[10];
    const float* dcn_w2 = (const float*)d_in[11];
    const float* dcn_b2 = (const float*)d_in[12];
    const float* bn_g2  = (const float*)d_in[13];
    const float* bn_b2  = (const float*)d_in[14];
    const float* bn_m2  = (const float*)d_in[15];
    const float* bn_v2  = (const float*)d_in[16];
    const float* cam_w1 = (const float*)d_in[17];
    const float* cam_w2 = (const float*)d_in[18];
    float* out = (float*)d_out;

    float* ws = (float*)d_ws;
    float* om = ws;                       // 8*27*9216 = 1,990,656 f32
    float* o1 = om + 1990656;             // 9,437,184 f32
    float* o2 = o1 + 9437184;             // 9,437,184 f32
    _Float16* wt1h = (_Float16*)(o2 + 9437184);   // 147,456 f16 each
    _Float16* wt1l = wt1h + 147456;
    _Float16* wt2h = wt1l + 147456;
    _Float16* wt2l = wt2h + 147456;
    _Float16* ow1h = wt2l + 147456;               // 36,864 f16 each
    _Float16* ow1l = ow1h + 36864;
    _Float16* ow2h = ow1l + 36864;
    _Float16* ow2l = ow2h + 36864;
    float* mxv = (float*)(ow2l + 36864);
    float* avv = mxv + 1024;
    float* chv = avv + 1024;

    wt_split <<<576, 256, 0, stream>>>(dcn_w1, wt1h, wt1l);
    wt_split <<<576, 256, 0, stream>>>(dcn_w2, wt2h, wt2l);
    offw_split<<<144, 256, 0, stream>>>(off_w1, ow1h, ow1l);
    offw_split<<<144, 256, 0, stream>>>(off_w2, ow2h, ow2l);

    off_mfma<<<1152, 256, 0, stream>>>(x, ow1h, ow1l, off_b1, om);
    dcn_mfma<<<1152, 256, 0, stream>>>(x, om, wt1h, wt1l, dcn_b1,
                                       bn_g1, bn_b1, bn_m1, bn_v1, o1);
    off_mfma<<<1152, 256, 0, stream>>>(o1, ow2h, ow2l, off_b2, om);
    dcn_mfma<<<1152, 256, 0, stream>>>(o1, om, wt2h, wt2l, dcn_b2,
                                       bn_g2, bn_b2, bn_m2, bn_v2, o2);

    reduce_bc<<<B * C, 256, 0, stream>>>(o2, mxv, avv);
    cam_gate <<<B, 128, 0, stream>>>(mxv, avv, cam_w1, cam_w2, chv);
    scale_out<<<(B * C * HW / 4 + 255) / 256, 256, 0, stream>>>(o2, chv, out);
}